// Round 1
// baseline (4313.025 us; speedup 1.0000x reference)
//
#include <hip/hip_runtime.h>
#include <hip/hip_bf16.h>
#include <cstdint>
#include <cstddef>

#define BB 16
#define TT 256
#define EE 256
#define HH 512
#define VV 32000
#define G4 2048   // 4*H

typedef __attribute__((ext_vector_type(8))) short short8;   // 8 bf16 (4 VGPRs)
typedef __attribute__((ext_vector_type(4))) float f32x4;    // 4 f32 acc

// f32 -> bf16 with round-to-nearest-even (manual, avoids API differences)
__device__ __forceinline__ short f2bf(float x){
    union { float f; unsigned u; } v; v.f = x;
    unsigned r = v.u + 0x7fffu + ((v.u >> 16) & 1u);
    return (short)(r >> 16);
}

__device__ __forceinline__ float sigf(float x){ return 1.0f / (1.0f + __expf(-x)); }
__device__ __forceinline__ float tanh_(float x){ return 2.0f / (1.0f + __expf(-2.0f * x)) - 1.0f; }

// ---------------- K0a: embedding gather + cvt to bf16 -----------------------
// xbf[m][0:256] = bf16(emb[tokens[m]][:]), m in [0,4096)
__global__ void k_gather(const int* __restrict__ tok, const float* __restrict__ emb,
                         short* __restrict__ xbf){
    int m = blockIdx.x;
    int t = tok[m];
    int k = threadIdx.x;               // 256 threads == EE
    xbf[(size_t)m * EE + k] = f2bf(emb[(size_t)t * EE + k]);
}

// ---------------- K0b: transpose + cvt: in f32 [K][N] -> out bf16 [N][K] ----
__global__ void k_transpose(const float* __restrict__ in, short* __restrict__ out,
                            int K, int N){
    __shared__ short tile[64][65];
    int kb = blockIdx.x * 64, nb = blockIdx.y * 64;
    int c = threadIdx.x & 63, r0 = threadIdx.x >> 6;
    for (int r = r0; r < 64; r += 4)
        tile[r][c] = f2bf(in[(size_t)(kb + r) * N + nb + c]);
    __syncthreads();
    for (int r = r0; r < 64; r += 4)
        out[(size_t)(nb + r) * K + kb + c] = tile[c][r];
}

// ---------------- K1: xW1 = x @ W1 + b1  (bf16 MFMA, f32 out) ---------------
// A: xbf [4096][256] bf16, Bsw: W1sw [2048][256] bf16, out: [4096][2048] f32
__global__ __launch_bounds__(256) void k_xw1(const short* __restrict__ A,
                                             const short* __restrict__ Bsw,
                                             const float* __restrict__ bias,
                                             float* __restrict__ out){
    int g = blockIdx.x;
    int mb = g & 15, nb = g >> 4;                    // 16 x 64 blocks
    int wave = threadIdx.x >> 6, lane = threadIdx.x & 63;
    int ln = lane & 15, q = lane >> 4;
    int col0 = nb * 32 + ln;
    short8 bf[2][8];
    for (int nt = 0; nt < 2; nt++){
        const short* bp = Bsw + (size_t)(col0 + nt * 16) * EE + q * 8;
        for (int ks = 0; ks < 8; ks++) bf[nt][ks] = *(const short8*)(bp + ks * 32);
    }
    float bi0 = bias[col0], bi1 = bias[col0 + 16];
    int mrow0 = mb * 256 + wave * 64;
    for (int mt = 0; mt < 4; mt++){
        f32x4 a0 = {bi0, bi0, bi0, bi0}, a1 = {bi1, bi1, bi1, bi1};
        const short* ap = A + (size_t)(mrow0 + mt * 16 + ln) * EE + q * 8;
        for (int ks = 0; ks < 8; ks++){
            short8 af = *(const short8*)(ap + ks * 32);
            a0 = __builtin_amdgcn_mfma_f32_16x16x32_bf16(af, bf[0][ks], a0, 0, 0, 0);
            a1 = __builtin_amdgcn_mfma_f32_16x16x32_bf16(af, bf[1][ks], a1, 0, 0, 0);
        }
        for (int r = 0; r < 4; r++){
            int row = mrow0 + mt * 16 + q * 4 + r;
            out[(size_t)row * G4 + nb * 32 + ln]      = a0[r];
            out[(size_t)row * G4 + nb * 32 + 16 + ln] = a1[r];
        }
    }
}

// ---------------- K2: fused 2-layer LSTM recurrence (persistent) ------------
// 64 WGs x 256 thr. WGs [0,32): layer1, [32,64): layer2 (one step behind).
// Wave v handles gate v for h-col block [w*16, w*16+16). U/W frags in VGPRs.
__global__ __launch_bounds__(256) void k_lstm(
        const float* __restrict__ xW1,   // [b*T+t][2048] f32 (includes b1)
        const float* __restrict__ U1,    // [512][2048] f32
        const float* __restrict__ W2,    // [512][2048] f32
        const float* __restrict__ U2,    // [512][2048] f32
        const float* __restrict__ b2,    // [2048] f32
        short* __restrict__ hs1,         // [T][B][H] bf16
        short* __restrict__ hs2,         // [T][B][H] bf16
        unsigned* bar){                  // [0]=arrive count, [1]=release phase
    __shared__ float zl[4][16][16];
    int wg = blockIdx.x;
    int layer = wg >> 5;
    int w = wg & 31;
    int wave = threadIdx.x >> 6, lane = threadIdx.x & 63;
    int ln = lane & 15, q = lane >> 4;
    int col = wave * HH + w * 16 + ln;   // z-column in [0,2048)

    short8 fU1[16], fW2[16], fU2[16];
    float b2c = 0.f;
    if (layer == 0){
        for (int ks = 0; ks < 16; ks++){
            short8 v;
            for (int j = 0; j < 8; j++)
                v[j] = f2bf(U1[(size_t)(ks * 32 + q * 8 + j) * G4 + col]);
            fU1[ks] = v;
        }
    } else {
        for (int ks = 0; ks < 16; ks++){
            short8 v, u;
            for (int j = 0; j < 8; j++){
                v[j] = f2bf(W2[(size_t)(ks * 32 + q * 8 + j) * G4 + col]);
                u[j] = f2bf(U2[(size_t)(ks * 32 + q * 8 + j) * G4 + col]);
            }
            fW2[ks] = v; fU2[ks] = u;
        }
        b2c = b2[col];
    }

    int bc = threadIdx.x >> 4, hc = threadIdx.x & 15;  // gate-update ownership
    float creg = 0.f;
    unsigned phase = 0;

    for (int s = 0; s <= TT; s++){
        bool active;
        if (layer == 0){
            active = (s < TT);
            if (active){
                f32x4 acc;
                for (int r = 0; r < 4; r++)                    // C-init = xW1[b][s][col]
                    acc[r] = xW1[((size_t)(q * 4 + r) * TT + s) * G4 + col];
                if (s > 0){
                    const short* ap = hs1 + (size_t)(s - 1) * BB * HH + ln * HH + q * 8;
                    for (int ks = 0; ks < 16; ks++){
                        short8 af = *(const short8*)(ap + ks * 32);
                        acc = __builtin_amdgcn_mfma_f32_16x16x32_bf16(af, fU1[ks], acc, 0, 0, 0);
                    }
                }
                for (int r = 0; r < 4; r++) zl[wave][q * 4 + r][ln] = acc[r];
            }
        } else {
            active = (s >= 1);
            if (active){
                int t2 = s - 1;
                f32x4 acc = {b2c, b2c, b2c, b2c};
                const short* ap1 = hs1 + (size_t)t2 * BB * HH + ln * HH + q * 8;
                for (int ks = 0; ks < 16; ks++){
                    short8 af = *(const short8*)(ap1 + ks * 32);
                    acc = __builtin_amdgcn_mfma_f32_16x16x32_bf16(af, fW2[ks], acc, 0, 0, 0);
                }
                if (t2 > 0){
                    const short* ap2 = hs2 + (size_t)(t2 - 1) * BB * HH + ln * HH + q * 8;
                    for (int ks = 0; ks < 16; ks++){
                        short8 af = *(const short8*)(ap2 + ks * 32);
                        acc = __builtin_amdgcn_mfma_f32_16x16x32_bf16(af, fU2[ks], acc, 0, 0, 0);
                    }
                }
                for (int r = 0; r < 4; r++) zl[wave][q * 4 + r][ln] = acc[r];
            }
        }
        __syncthreads();
        if (active){
            float zi = zl[0][bc][hc], zf = zl[1][bc][hc];
            float zg = zl[2][bc][hc], zo = zl[3][bc][hc];
            float ig = sigf(zi), fg = sigf(zf), gg = tanh_(zg), og = sigf(zo);
            creg = fg * creg + ig * gg;
            float h = og * tanh_(creg);
            int tcur = (layer == 0) ? s : s - 1;
            short* hp = (layer == 0 ? hs1 : hs2)
                        + (size_t)tcur * BB * HH + bc * HH + w * 16 + hc;
            *hp = f2bf(h);
        }
        // ---- grid barrier (sense-reversing, agent scope) ----
        __syncthreads();
        phase++;
        if (threadIdx.x == 0){
            __threadfence();
            unsigned old = __hip_atomic_fetch_add(&bar[0], 1u, __ATOMIC_ACQ_REL,
                                                  __HIP_MEMORY_SCOPE_AGENT);
            if (old == 63u){
                __hip_atomic_store(&bar[0], 0u, __ATOMIC_RELAXED, __HIP_MEMORY_SCOPE_AGENT);
                __hip_atomic_store(&bar[1], phase, __ATOMIC_RELEASE, __HIP_MEMORY_SCOPE_AGENT);
            } else {
                while (__hip_atomic_load(&bar[1], __ATOMIC_ACQUIRE,
                                         __HIP_MEMORY_SCOPE_AGENT) < phase){
                    __builtin_amdgcn_s_sleep(1);
                }
            }
            __threadfence();
        }
        __syncthreads();
    }
}

// ---------------- K3: logits = hs2 @ Wd + bd (bf16 MFMA, f32 out) -----------
// A: hs2 [t][b][H] bf16 (row remap m=(b,t) -> t*16+b), Bsw: Wdsw [32000][512]
__global__ __launch_bounds__(256) void k_dense(const short* __restrict__ A,
                                               const short* __restrict__ Bsw,
                                               const float* __restrict__ bias,
                                               float* __restrict__ out){
    int g = blockIdx.x;
    // XCD swizzle: xcd = g%8 owns nb range [xcd*125, xcd*125+125), mb inner.
    int xcd = g & 7;
    int gx  = g >> 3;            // [0,2000)
    int nb  = xcd * 125 + (gx >> 4);
    int mb  = gx & 15;
    int wave = threadIdx.x >> 6, lane = threadIdx.x & 63;
    int ln = lane & 15, q = lane >> 4;
    int col0 = nb * 32 + ln;
    short8 bf[2][16];
    for (int nt = 0; nt < 2; nt++){
        const short* bp = Bsw + (size_t)(col0 + nt * 16) * HH + q * 8;
        for (int ks = 0; ks < 16; ks++) bf[nt][ks] = *(const short8*)(bp + ks * 32);
    }
    float bi0 = bias[col0], bi1 = bias[col0 + 16];
    int mrow0 = mb * 256 + wave * 64;
    for (int mt = 0; mt < 4; mt++){
        int m = mrow0 + mt * 16 + ln;
        int arow = (m & 255) * BB + (m >> 8);    // t*16 + b
        const short* ap = A + (size_t)arow * HH + q * 8;
        f32x4 a0 = {bi0, bi0, bi0, bi0}, a1 = {bi1, bi1, bi1, bi1};
        for (int ks = 0; ks < 16; ks++){
            short8 af = *(const short8*)(ap + ks * 32);
            a0 = __builtin_amdgcn_mfma_f32_16x16x32_bf16(af, bf[0][ks], a0, 0, 0, 0);
            a1 = __builtin_amdgcn_mfma_f32_16x16x32_bf16(af, bf[1][ks], a1, 0, 0, 0);
        }
        for (int r = 0; r < 4; r++){
            int row = mrow0 + mt * 16 + q * 4 + r;
            out[(size_t)row * VV + nb * 32 + ln]      = a0[r];
            out[(size_t)row * VV + nb * 32 + 16 + ln] = a1[r];
        }
    }
}

extern "C" void kernel_launch(void* const* d_in, const int* in_sizes, int n_in,
                              void* d_out, int out_size, void* d_ws, size_t ws_size,
                              hipStream_t stream){
    const int*   tokens = (const int*)  d_in[0];
    const float* emb    = (const float*)d_in[1];
    const float* W1     = (const float*)d_in[2];
    const float* U1     = (const float*)d_in[3];
    const float* b1     = (const float*)d_in[4];
    const float* W2     = (const float*)d_in[5];
    const float* U2     = (const float*)d_in[6];
    const float* b2     = (const float*)d_in[7];
    const float* Wd     = (const float*)d_in[8];
    const float* bd     = (const float*)d_in[9];
    float* out = (float*)d_out;

    char* ws = (char*)d_ws;
    size_t off = 0;
    auto alloc = [&](size_t bytes){
        void* p = ws + off; off += (bytes + 255) & ~(size_t)255; return p;
    };
    float*    xW1  = (float*)   alloc((size_t)4096 * 2048 * 4);   // 32 MB
    short*    hs1  = (short*)   alloc((size_t)256 * 16 * 512 * 2);//  4 MB
    short*    hs2  = (short*)   alloc((size_t)256 * 16 * 512 * 2);//  4 MB
    short*    xbf  = (short*)   alloc((size_t)4096 * 256 * 2);    //  2 MB
    short*    W1sw = (short*)   alloc((size_t)2048 * 256 * 2);    //  1 MB
    short*    Wdsw = (short*)   alloc((size_t)32000 * 512 * 2);   // 32 MB
    unsigned* bar  = (unsigned*)alloc(256);

    hipMemsetAsync(bar, 0, 8, stream);
    k_gather<<<4096, 256, 0, stream>>>(tokens, emb, xbf);
    k_transpose<<<dim3(4, 32), 256, 0, stream>>>(W1, W1sw, 256, 2048);
    k_transpose<<<dim3(8, 500), 256, 0, stream>>>(Wd, Wdsw, 512, 32000);
    k_xw1<<<1024, 256, 0, stream>>>(xbf, W1sw, b1, xW1);
    k_lstm<<<64, 256, 0, stream>>>(xW1, U1, W2, U2, b2, hs1, hs2, bar);
    k_dense<<<16000, 256, 0, stream>>>(hs2, Wdsw, bd, out);
}